// Round 10
// baseline (60.110 us; speedup 1.0000x reference)
//
#include <hip/hip_runtime.h>
#include <hip/hip_bf16.h>

#define F_DIM 64
#define B_DIM 64
#define C_DIM 1024
#define BM 64
#define BN 128
#define BK 64
#define NT (C_DIM / BK)       // 16 K-steps
#define NTILES (C_DIM / BN)   // 8 o-tiles per feature
#define THREADS 512
#define BSTRIDE 132           // bounce row stride in f32 (pad: 132%32=4 -> 2-way max)

using f32x4  = __attribute__((ext_vector_type(4))) float;
using bf16x8 = __attribute__((ext_vector_type(8))) short;
using s16x4  = __attribute__((ext_vector_type(4))) short;

// fp32 -> bf16 round-to-nearest-even
static __device__ __forceinline__ short f2bf(float f) {
    unsigned u = __float_as_uint(f);
    unsigned r = (u + 0x7fffu + ((u >> 16) & 1u)) >> 16;
    return (short)r;
}

__global__ __launch_bounds__(THREADS, 4)
void channelfc_kernel(const float* __restrict__ x,
                      const float* __restrict__ w,
                      const float* __restrict__ bias,
                      float* __restrict__ out)
{
    // R10: single change vs R5 (58.3us, best): LDS-bounce COALESCED epilogue.
    // Old epilogue: 16 scalar stores/thread, 64B granule per instruction into
    // 4KB-strided rows -> possible L2 write-allocate read amp (+up to 17MB)
    // and partial-line write bursts. New: acc -> LDS (stride-132 pad), then
    // read back so each 32-lane half-wave stores 512B CONTIGUOUS (full lines),
    // bias folded in vectorized. K-loop, staging, swizzles identical to R5.
    //
    // T1 XCD swizzle: block n -> XCD n%8; XCD x owns features {x, x+8, ...},
    // 8 o-tiles of one f consecutive -> X_f (256 KB) fetched ~once per XCD.
    const int n    = blockIdx.x;       // 0..511
    const int xcd  = n & 7;
    const int j    = n >> 3;           // 0..63 within this XCD
    const int f    = xcd + 8 * (j >> 3);
    const int bx   = j & 7;            // o-tile index
    const int ocol0 = bx * BN;

    const int tid   = threadIdx.x;
    const int lane  = tid & 63;
    const int wid   = tid >> 6;   // 0..7
    const int wr    = wid >> 2;   // 0..1 -> rows wr*32..+32
    const int wc    = wid & 3;    // 0..3 -> cols wc*32..+32

    // Tiles while K-looping; bounce buffer for the epilogue (union: the
    // epilogue only touches it after a barrier that retires all tile reads).
    __shared__ union {
        struct { short A[2][BM * BK]; short B[2][BN * BK]; } t;  // 48 KB
        float bounce[B_DIM * BSTRIDE];                           // 33.8 KB
    } sh;

    const float* xA = x + (size_t)f * C_DIM;                       // + b*(F*C) + c
    const float* wB = w + ((size_t)f * C_DIM + ocol0) * C_DIM;     // + o*C + c

    f32x4 ra[2];   // X staging: 1024 float4 / 512 thr = 2 each
    f32x4 rb[4];   // W staging: 2048 float4 / 512 thr = 4 each

    auto load_tile = [&](int t) {
        const int k0 = t * BK;
        #pragma unroll
        for (int i = 0; i < 2; ++i) {
            int id = i * THREADS + tid, row = id >> 4, k4 = id & 15;   // 16 float4 per row
            ra[i] = *(const f32x4*)(xA + (size_t)row * (F_DIM * C_DIM) + k0 + k4 * 4);
        }
        #pragma unroll
        for (int i = 0; i < 4; ++i) {
            int id = i * THREADS + tid, row = id >> 4, k4 = id & 15;
            rb[i] = *(const f32x4*)(wB + (size_t)row * C_DIM + k0 + k4 * 4);
        }
    };

    auto store_tile = [&](int buf) {
        #pragma unroll
        for (int i = 0; i < 2; ++i) {
            int id = i * THREADS + tid, row = id >> 4, k4 = id & 15;
            int byte = (k4 * 8) ^ ((row & 7) << 4);                // T2 swizzle, 16B-granular
            s16x4 v; v[0]=f2bf(ra[i][0]); v[1]=f2bf(ra[i][1]); v[2]=f2bf(ra[i][2]); v[3]=f2bf(ra[i][3]);
            *(s16x4*)((char*)&sh.t.A[buf][0] + row * 128 + byte) = v;
        }
        #pragma unroll
        for (int i = 0; i < 4; ++i) {
            int id = i * THREADS + tid, row = id >> 4, k4 = id & 15;
            int byte = (k4 * 8) ^ ((row & 7) << 4);
            s16x4 v; v[0]=f2bf(rb[i][0]); v[1]=f2bf(rb[i][1]); v[2]=f2bf(rb[i][2]); v[3]=f2bf(rb[i][3]);
            *(s16x4*)((char*)&sh.t.B[buf][0] + row * 128 + byte) = v;
        }
    };

    f32x4 acc[2][2] = {};   // wave sub-tile 32x32 = 2 M-frags x 2 N-frags

    auto compute = [&](int buf) {
        #pragma unroll
        for (int ks = 0; ks < 2; ++ks) {
            const int kbyte = ks * 64 + (lane >> 4) * 16;   // frag: k = ks*32 + (lane>>4)*8 + j
            bf16x8 af[2], bfr[2];
            #pragma unroll
            for (int mt = 0; mt < 2; ++mt) {
                int row = wr * 32 + mt * 16 + (lane & 15);
                af[mt] = *(const bf16x8*)((const char*)&sh.t.A[buf][0] + row * 128 + (kbyte ^ ((row & 7) << 4)));
            }
            #pragma unroll
            for (int nt = 0; nt < 2; ++nt) {
                int row = wc * 32 + nt * 16 + (lane & 15);
                bfr[nt] = *(const bf16x8*)((const char*)&sh.t.B[buf][0] + row * 128 + (kbyte ^ ((row & 7) << 4)));
            }
            #pragma unroll
            for (int mt = 0; mt < 2; ++mt)
                #pragma unroll
                for (int nt = 0; nt < 2; ++nt)
                    acc[mt][nt] = __builtin_amdgcn_mfma_f32_16x16x32_bf16(af[mt], bfr[nt], acc[mt][nt], 0, 0, 0);
        }
    };

    // K-loop identical to R5 (best measured). Barrier safety: compute(t)
    // reads buf[t&1] after barrier(t) which store(t) wrote before it;
    // store(t+2) overwrites buf[t&1] only after barrier(t+1), which follows
    // compute(t)'s LDS reads in every wave's program order.
    load_tile(0);
    for (int t = 0; t < NT; ++t) {
        const int buf = t & 1;
        store_tile(buf);
        if (t + 1 < NT) load_tile(t + 1);
        __syncthreads();
        compute(buf);
    }

    // --- Epilogue: LDS bounce -> full-line coalesced stores ---
    // acc layout (m89-verified): col = lane&15 (-> o), row = (lane>>4)*4 + r (-> b)
    __syncthreads();   // all tile reads retired in every wave -> union reuse safe
    {
        const int col_base = wc * 32 + (lane & 15);
        const int row_base = wr * 32 + (lane >> 4) * 4;
        #pragma unroll
        for (int mt = 0; mt < 2; ++mt)
            #pragma unroll
            for (int nt = 0; nt < 2; ++nt)
                #pragma unroll
                for (int r = 0; r < 4; ++r)
                    sh.bounce[(row_base + mt * 16 + r) * BSTRIDE + col_base + nt * 16] = acc[mt][nt][r];
    }
    __syncthreads();
    // Read back + bias + store: 2048 f32x4 / 512 thr = 4 iters. Lanes 0..31
    // of a wave share one b-row -> each half-wave stores 512B contiguous
    // (4 full 128B lines per half-wave); no partial-line granules.
    #pragma unroll
    for (int i2 = 0; i2 < 4; ++i2) {
        int flat = i2 * THREADS + tid;   // 0..2047
        int row  = flat >> 5;            // b = 0..63
        int seg  = flat & 31;            // 16B segment within the 512B o-range
        f32x4 v  = *(const f32x4*)&sh.bounce[row * BSTRIDE + seg * 4];
        f32x4 bv = *(const f32x4*)&bias[f * C_DIM + ocol0 + seg * 4];
        v += bv;
        *(f32x4*)&out[((size_t)row * F_DIM + f) * C_DIM + ocol0 + seg * 4] = v;
    }
}

extern "C" void kernel_launch(void* const* d_in, const int* in_sizes, int n_in,
                              void* d_out, int out_size, void* d_ws, size_t ws_size,
                              hipStream_t stream) {
    const float* x    = (const float*)d_in[0];
    const float* w    = (const float*)d_in[1];
    const float* bias = (const float*)d_in[2];
    float* out        = (float*)d_out;
    // 512 blocks (2/CU), XCD-aware index decode in-kernel.
    channelfc_kernel<<<dim3(NTILES * F_DIM), dim3(THREADS), 0, stream>>>(x, w, bias, out);
}